// Round 1
// 742.151 us; speedup vs baseline: 1.0124x; 1.0124x over previous
//
#include <hip/hip_runtime.h>
#include <cmath>

typedef __bf16 bf16_t;
typedef bf16_t bf16x8 __attribute__((ext_vector_type(8)));
typedef float floatx4 __attribute__((ext_vector_type(4)));

#define NFEAT 26
#define DIM 64
#define DENSE_IN 13
#define CARD 100000
#define HBOT 8
#define KSTEPS 54   // 52 feature K-steps + 2 dense K-steps

// ---- one-time: build tw1 B-fragments (bf16, MFMA lane order) in workspace ----
__global__ __launch_bounds__(256) void prep_bfrag(
    const float* __restrict__ tw1, bf16_t* __restrict__ bws)
{
    int slot = blockIdx.x * 256 + threadIdx.x;
    if (slot >= KSTEPS * 64) return;
    int t  = slot >> 6;
    int l  = slot & 63;
    int n  = l & 15;
    int k0 = t * 32 + (l >> 4) * 8;
    bf16x8 v;
    #pragma unroll
    for (int j = 0; j < 8; ++j) v[j] = (bf16_t)tw1[(k0 + j) * 16 + n];
    *(bf16x8*)(&bws[slot * 8]) = v;
}

// ---- main: 16 samples/block, K-split across 4 waves ----
__global__ __launch_bounds__(256, 4) void dlrm_main(
    const float* __restrict__ dense_x,
    const int*   __restrict__ sparse_x,
    const float* __restrict__ tables,
    const float* __restrict__ w1, const float* __restrict__ b1,
    const float* __restrict__ w2, const float* __restrict__ b2,
    const bf16_t* __restrict__ bws,
    const float* __restrict__ tb1, const float* __restrict__ tw2,
    const float* __restrict__ tb2,
    float* __restrict__ out)
{
    __shared__ int idx_lds[16 * NFEAT];      // 1664 B
    __shared__ floatx4 red[3][64];           // 3072 B: partials from waves 1..3

    const int tid  = threadIdx.x;
    const int blk  = blockIdx.x;
    const int lane = tid & 63;
    const int w    = tid >> 6;
    const int m    = lane & 15;   // sample within block / hidden idx in epilogue
    const int q    = lane >> 4;

    // stage this block's sparse indices (16 samples x 26 feats), coalesced
    const int* sp = sparse_x + blk * 16 * NFEAT;
    for (int i = tid; i < 16 * NFEAT; i += 256) idx_lds[i] = sp[i];

    floatx4 acc = {0.f, 0.f, 0.f, 0.f};

    // dense K-steps (t = 52 + w) on waves 0/1: bottom MLP fully in-register
    if (w < 2) {
        const float* dx = dense_x + (blk * 16 + m) * DENSE_IN;
        float x[DENSE_IN];
        #pragma unroll
        for (int i = 0; i < DENSE_IN; ++i) x[i] = dx[i];
        float h8[HBOT];
        #pragma unroll
        for (int j = 0; j < HBOT; ++j) {
            float a0 = b1[j];
            #pragma unroll
            for (int i = 0; i < DENSE_IN; ++i) a0 = fmaf(x[i], w1[i * HBOT + j], a0);
            h8[j] = fmaxf(a0, 0.f);
        }
        const int d0 = w * 32 + q * 8;
        bf16x8 a;
        #pragma unroll
        for (int jj = 0; jj < 8; ++jj) {
            float a0 = b2[d0 + jj];
            #pragma unroll
            for (int j = 0; j < HBOT; ++j) a0 = fmaf(h8[j], w2[j * DIM + d0 + jj], a0);
            a[jj] = (bf16_t)a0;
        }
        bf16x8 b = *(const bf16x8*)(bws + ((52 + w) * 64 + lane) * 8);
        acc = __builtin_amdgcn_mfma_f32_16x16x32_bf16(a, b, acc, 0, 0, 0);
    }

    __syncthreads();

    // 13 feature K-steps per wave, stride-4 across waves: t = w, w+4, ..., w+48
    const int* myidx = &idx_lds[m * NFEAT];
    #pragma unroll
    for (int u = 0; u < 13; ++u) {
        const int t = w + 4 * u;
        const int f = t >> 1;
        const int h = t & 1;
        const int idx = myidx[f];
        const float* row = tables + (f * CARD + idx) * DIM + h * 32 + q * 8;
        const float4 p0 = *(const float4*)(row);
        const float4 p1 = *(const float4*)(row + 4);
        bf16x8 a;
        a[0] = (bf16_t)p0.x; a[1] = (bf16_t)p0.y;
        a[2] = (bf16_t)p0.z; a[3] = (bf16_t)p0.w;
        a[4] = (bf16_t)p1.x; a[5] = (bf16_t)p1.y;
        a[6] = (bf16_t)p1.z; a[7] = (bf16_t)p1.w;
        bf16x8 b = *(const bf16x8*)(bws + (t * 64 + lane) * 8);
        acc = __builtin_amdgcn_mfma_f32_16x16x32_bf16(a, b, acc, 0, 0, 0);
    }

    // cross-wave reduction of partial accumulators
    if (w > 0) red[w - 1][lane] = acc;
    __syncthreads();
    if (w == 0) {
        acc += red[0][lane];
        acc += red[1][lane];
        acc += red[2][lane];
        const float bias = tb1[m];
        const float wout = tw2[m];
        float p[4];
        #pragma unroll
        for (int i = 0; i < 4; ++i) p[i] = fmaxf(acc[i] + bias, 0.f) * wout;
        #pragma unroll
        for (int off = 1; off < 16; off <<= 1) {
            #pragma unroll
            for (int i = 0; i < 4; ++i) p[i] += __shfl_xor(p[i], off, 64);
        }
        if (m == 0) {
            const float bout = tb2[0];
            float4 o;
            o.x = 1.f / (1.f + expf(-(p[0] + bout)));
            o.y = 1.f / (1.f + expf(-(p[1] + bout)));
            o.z = 1.f / (1.f + expf(-(p[2] + bout)));
            o.w = 1.f / (1.f + expf(-(p[3] + bout)));
            *(float4*)(out + blk * 16 + q * 4) = o;
        }
    }
}

extern "C" void kernel_launch(void* const* d_in, const int* in_sizes, int n_in,
                              void* d_out, int out_size, void* d_ws, size_t ws_size,
                              hipStream_t stream) {
    const float* dense_x = (const float*)d_in[0];
    const int*   sparse_x = (const int*)d_in[1];
    const float* tables  = (const float*)d_in[2];
    const float* w1  = (const float*)d_in[3];
    const float* b1  = (const float*)d_in[4];
    const float* w2  = (const float*)d_in[5];
    const float* b2  = (const float*)d_in[6];
    const float* tw1 = (const float*)d_in[7];
    const float* tb1 = (const float*)d_in[8];
    const float* tw2 = (const float*)d_in[9];
    const float* tb2 = (const float*)d_in[10];
    float* out = (float*)d_out;
    bf16_t* bws = (bf16_t*)d_ws;   // 54*64*8*2 B = 55296 B, rebuilt every call

    prep_bfrag<<<(KSTEPS * 64 + 255) / 256, 256, 0, stream>>>(tw1, bws);
    dlrm_main<<<16384 / 16, 256, 0, stream>>>(dense_x, sparse_x, tables,
                                              w1, b1, w2, b2, bws,
                                              tb1, tw2, tb2, out);
}

// Round 2
// 740.488 us; speedup vs baseline: 1.0147x; 1.0022x over previous
//
#include <hip/hip_runtime.h>
#include <cmath>

typedef __bf16 bf16_t;
typedef bf16_t bf16x8 __attribute__((ext_vector_type(8)));
typedef float floatx4 __attribute__((ext_vector_type(4)));

#define NFEAT 26
#define DIM 64
#define DENSE_IN 13
#define CARD 100000
#define HBOT 8
#define KSTEPS 54   // 52 feature K-steps + 2 dense K-steps

// ---- one-time: build tw1 B-fragments (bf16, MFMA lane order) in workspace ----
__global__ __launch_bounds__(256) void prep_bfrag(
    const float* __restrict__ tw1, bf16_t* __restrict__ bws)
{
    int slot = blockIdx.x * 256 + threadIdx.x;
    if (slot >= KSTEPS * 64) return;
    int t  = slot >> 6;
    int l  = slot & 63;
    int n  = l & 15;
    int k0 = t * 32 + (l >> 4) * 8;
    bf16x8 v;
    #pragma unroll
    for (int j = 0; j < 8; ++j) v[j] = (bf16_t)tw1[(k0 + j) * 16 + n];
    *(bf16x8*)(&bws[slot * 8]) = v;
}

// ---- main: 16 samples/block, K-split across 4 waves, no staging barrier ----
__global__ __launch_bounds__(256, 4) void dlrm_main(
    const float* __restrict__ dense_x,
    const int*   __restrict__ sparse_x,
    const float* __restrict__ tables,
    const float* __restrict__ w1, const float* __restrict__ b1,
    const float* __restrict__ w2, const float* __restrict__ b2,
    const bf16_t* __restrict__ bws,
    const float* __restrict__ tb1, const float* __restrict__ tw2,
    const float* __restrict__ tb2,
    float* __restrict__ out)
{
    __shared__ floatx4 red[3][64];           // 3072 B: partials from waves 1..3

    const int tid  = threadIdx.x;
    const int blk  = blockIdx.x;
    const int lane = tid & 63;
    const int w    = tid >> 6;
    const int m    = lane & 15;   // sample within block / hidden idx in epilogue
    const int q    = lane >> 4;

    floatx4 acc = {0.f, 0.f, 0.f, 0.f};

    // 13 feature K-steps per wave, stride-4 across waves: t = w, w+4, ..., w+48
    // indices read directly from global (L2-resident) -> gathers issue immediately
    const int* sp = sparse_x + (blk * 16 + m) * NFEAT;
    #pragma unroll
    for (int u = 0; u < 13; ++u) {
        const int t = w + 4 * u;
        const int f = t >> 1;
        const int h = t & 1;
        const int idx = sp[f];
        const float* row = tables + (f * CARD + idx) * DIM + h * 32 + q * 8;
        const float4 p0 = *(const float4*)(row);
        const float4 p1 = *(const float4*)(row + 4);
        bf16x8 a;
        a[0] = (bf16_t)p0.x; a[1] = (bf16_t)p0.y;
        a[2] = (bf16_t)p0.z; a[3] = (bf16_t)p0.w;
        a[4] = (bf16_t)p1.x; a[5] = (bf16_t)p1.y;
        a[6] = (bf16_t)p1.z; a[7] = (bf16_t)p1.w;
        bf16x8 b = *(const bf16x8*)(bws + (t * 64 + lane) * 8);
        acc = __builtin_amdgcn_mfma_f32_16x16x32_bf16(a, b, acc, 0, 0, 0);
    }

    // dense K-step (t = 52 + w) on waves 0/1: bottom MLP fully in-register
    if (w < 2) {
        const float* dx = dense_x + (blk * 16 + m) * DENSE_IN;
        float x[DENSE_IN];
        #pragma unroll
        for (int i = 0; i < DENSE_IN; ++i) x[i] = dx[i];
        float h8[HBOT];
        #pragma unroll
        for (int j = 0; j < HBOT; ++j) {
            float a0 = b1[j];
            #pragma unroll
            for (int i = 0; i < DENSE_IN; ++i) a0 = fmaf(x[i], w1[i * HBOT + j], a0);
            h8[j] = fmaxf(a0, 0.f);
        }
        const int d0 = w * 32 + q * 8;
        bf16x8 a;
        #pragma unroll
        for (int jj = 0; jj < 8; ++jj) {
            float a0 = b2[d0 + jj];
            #pragma unroll
            for (int j = 0; j < HBOT; ++j) a0 = fmaf(h8[j], w2[j * DIM + d0 + jj], a0);
            a[jj] = (bf16_t)a0;
        }
        bf16x8 b = *(const bf16x8*)(bws + ((52 + w) * 64 + lane) * 8);
        acc = __builtin_amdgcn_mfma_f32_16x16x32_bf16(a, b, acc, 0, 0, 0);
    }

    // cross-wave reduction of partial accumulators
    if (w > 0) red[w - 1][lane] = acc;
    __syncthreads();
    if (w == 0) {
        acc += red[0][lane];
        acc += red[1][lane];
        acc += red[2][lane];
        const float bias = tb1[m];
        const float wout = tw2[m];
        float p[4];
        #pragma unroll
        for (int i = 0; i < 4; ++i) p[i] = fmaxf(acc[i] + bias, 0.f) * wout;
        #pragma unroll
        for (int off = 1; off < 16; off <<= 1) {
            #pragma unroll
            for (int i = 0; i < 4; ++i) p[i] += __shfl_xor(p[i], off, 64);
        }
        if (m == 0) {
            const float bout = tb2[0];
            float4 o;
            o.x = 1.f / (1.f + expf(-(p[0] + bout)));
            o.y = 1.f / (1.f + expf(-(p[1] + bout)));
            o.z = 1.f / (1.f + expf(-(p[2] + bout)));
            o.w = 1.f / (1.f + expf(-(p[3] + bout)));
            *(float4*)(out + blk * 16 + q * 4) = o;
        }
    }
}

extern "C" void kernel_launch(void* const* d_in, const int* in_sizes, int n_in,
                              void* d_out, int out_size, void* d_ws, size_t ws_size,
                              hipStream_t stream) {
    const float* dense_x = (const float*)d_in[0];
    const int*   sparse_x = (const int*)d_in[1];
    const float* tables  = (const float*)d_in[2];
    const float* w1  = (const float*)d_in[3];
    const float* b1  = (const float*)d_in[4];
    const float* w2  = (const float*)d_in[5];
    const float* b2  = (const float*)d_in[6];
    const float* tw1 = (const float*)d_in[7];
    const float* tb1 = (const float*)d_in[8];
    const float* tw2 = (const float*)d_in[9];
    const float* tb2 = (const float*)d_in[10];
    float* out = (float*)d_out;
    bf16_t* bws = (bf16_t*)d_ws;   // 54*64*8*2 B = 55296 B, rebuilt every call

    prep_bfrag<<<(KSTEPS * 64 + 255) / 256, 256, 0, stream>>>(tw1, bws);
    dlrm_main<<<16384 / 16, 256, 0, stream>>>(dense_x, sparse_x, tables,
                                              w1, b1, w2, b2, bws,
                                              tb1, tw2, tb2, out);
}